// Round 4
// baseline (8962.423 us; speedup 1.0000x reference)
//
#include <hip/hip_runtime.h>
#include <stdint.h>

constexpr int kB   = 64;
constexpr int kTV  = 40;
constexpr int kF   = 2048;
constexpr int kH   = 1024;
constexpr int kV   = 32000;
constexpr int kNS  = 30;
constexpr int kCAP = 31;

typedef __attribute__((ext_vector_type(8))) short bf16x8;
typedef __attribute__((ext_vector_type(4))) float f32x4;

__device__ __forceinline__ float sigm(float x) { return 1.f / (1.f + __expf(-x)); }
__device__ __forceinline__ float tanh_fast(float x) {
    float e = __expf(2.f * x);
    return 1.f - 2.f / (e + 1.f);
}
__device__ __forceinline__ unsigned short f2bf(float x) {
    unsigned u = __float_as_uint(x);
    return (unsigned short)((u + 0x7fffu + ((u >> 16) & 1u)) >> 16);
}

__device__ __forceinline__ void gl16(const unsigned short* g, unsigned short* lds) {
    __builtin_amdgcn_global_load_lds(
        (const __attribute__((address_space(1))) unsigned int*)(g),
        (__attribute__((address_space(3))) unsigned int*)(lds), 16, 0, 0);
}

template <int N>
__device__ __forceinline__ void waitv() {
    asm volatile("s_waitcnt vmcnt(%0)" :: "n"(N) : "memory");
}
__device__ __forceinline__ void barrier_raw() {
    __builtin_amdgcn_s_barrier();
    asm volatile("" ::: "memory");
}

// ---- device-scope sync primitives (cross-XCD safe) ----
__device__ __forceinline__ void waitcnt_dev(int* cnt, int target) {
    if (threadIdx.x == 0) {
        while (__hip_atomic_load(cnt, __ATOMIC_ACQUIRE, __HIP_MEMORY_SCOPE_AGENT) < target)
            __builtin_amdgcn_s_sleep(2);
    }
    __syncthreads();
}
__device__ __forceinline__ void signal_dev(int* cnt) {
    __syncthreads();
    __threadfence();
    if (threadIdx.x == 0)
        __hip_atomic_fetch_add(cnt, 1, __ATOMIC_RELEASE, __HIP_MEMORY_SCOPE_AGENT);
}

// A-packed layout: [kt][ms][lane][j]; (row,col): ms=row>>4,
// lane=(row&15)+16*((kc>>2)&3), j=(kc&3)+4*(kc>>4), kc=col&31, kt=col>>5.
__device__ __forceinline__ void store_packedA(unsigned short* base, int row, int col,
                                              unsigned short v) {
    int kt = col >> 5, kc = col & 31, ms = row >> 4;
    int l = (row & 15) + (((kc >> 2) & 3) << 4);
    int j = (kc & 3) + ((kc >> 4) << 2);
    base[((((size_t)kt * 4 + ms) * 64 + l) << 3) + j] = v;
}

// ---------------- 3-deep pipelined MFMA K-loop ----------------
template <int NSPW, int KT>
__device__ __forceinline__ void mfma_kloop(
    const unsigned short* __restrict__ Ap, const unsigned short* __restrict__ Bp,
    unsigned short* Asm, unsigned short* Bsm, int w, int l, f32x4 acc[4][NSPW])
{
    constexpr int BSTEP = 2048 * NSPW;
    constexpr int LPT = 1 + NSPW;
    auto stage = [&](int t, int slot) {
        gl16(Ap + (size_t)t * 2048 + w * 512 + l * 8, Asm + slot * 2048 + w * 512);
#pragma unroll
        for (int i = 0; i < NSPW; ++i)
            gl16(Bp + (size_t)t * BSTEP + (w * NSPW + i) * 512 + l * 8,
                 Bsm + slot * BSTEP + (w * NSPW + i) * 512);
    };
    stage(0, 0); stage(1, 1); stage(2, 2);
#pragma unroll 1
    for (int t = 0; t < KT; ++t) {
        int slot = t % 3;
        int rem = KT - 1 - t;
        if (rem >= 2) waitv<2 * LPT>();
        else if (rem == 1) waitv<LPT>();
        else waitv<0>();
        barrier_raw();
        bf16x8 bfr[NSPW], afr[4];
#pragma unroll
        for (int i = 0; i < NSPW; ++i)
            bfr[i] = *(const bf16x8*)(Bsm + slot * BSTEP + ((w * NSPW + i) * 64 + l) * 8);
#pragma unroll
        for (int ms = 0; ms < 4; ++ms)
            afr[ms] = *(const bf16x8*)(Asm + slot * 2048 + (ms * 64 + l) * 8);
#pragma unroll
        for (int ms = 0; ms < 4; ++ms)
#pragma unroll
            for (int i = 0; i < NSPW; ++i)
                acc[ms][i] = __builtin_amdgcn_mfma_f32_16x16x32_bf16(
                    afr[ms], bfr[i], acc[ms][i], 0, 0, 0);
        __builtin_amdgcn_sched_barrier(0);
        barrier_raw();
        if (t + 3 < KT) stage(t + 3, slot);
    }
}

// ---------------- packing kernels (setup) ----------------
__global__ __launch_bounds__(256) void pack_rm(
    const float* __restrict__ p0, int ld0, int ksplit,
    const float* __restrict__ p1, int ld1,
    int NGRP, int GS, int HS, int KT,
    unsigned short* __restrict__ out)
{
    __shared__ unsigned short tile[16][136];
    int kb = blockIdx.x * 128;
    int grp = blockIdx.y;
    int row0 = (grp % NGRP) * GS + (grp / NGRP) * HS;
    int tid = threadIdx.x;
    int r = tid >> 5, c4 = (tid & 31) * 4;
#pragma unroll
    for (int pass = 0; pass < 2; ++pass) {
        int rr = r + pass * 8;
        int row = row0 + rr;
        int k = kb + c4;
        float4 v;
        if (k < ksplit) v = *(const float4*)(p0 + (size_t)row * ld0 + k);
        else            v = *(const float4*)(p1 + (size_t)row * ld1 + (k - ksplit));
        ushort4 o; o.x = f2bf(v.x); o.y = f2bf(v.y); o.z = f2bf(v.z); o.w = f2bf(v.w);
        *(ushort4*)&tile[rr][c4] = o;
    }
    __syncthreads();
    int ktl = tid >> 6, l = tid & 63, ul = l & 15, q = (l >> 4) & 3;
    __align__(16) unsigned short o2[8];
#pragma unroll
    for (int j = 0; j < 8; ++j) {
        int kc = (j & 3) + q * 4 + ((j >> 2) << 4);
        o2[j] = tile[ul][ktl * 32 + kc];
    }
    int kt = (kb >> 5) + ktl;
    size_t base = (((size_t)(grp / NGRP) * KT + kt) * NGRP + (grp % NGRP)) * 512;
    *(uint4*)(out + base + (size_t)l * 8) = *(const uint4*)o2;
}

__global__ __launch_bounds__(256) void pack_cm(const float* __restrict__ W,
                                               unsigned short* __restrict__ out)
{
    __shared__ unsigned short tile[32][136];
    int n0 = blockIdx.x * 128, k0 = blockIdx.y * 32;
    int tid = threadIdx.x;
    int r = tid >> 5, c4 = (tid & 31) * 4;
#pragma unroll
    for (int pass = 0; pass < 4; ++pass) {
        int rr = r + pass * 8;
        float4 v = *(const float4*)(W + (size_t)(k0 + rr) * kV + n0 + c4);
        ushort4 o; o.x = f2bf(v.x); o.y = f2bf(v.y); o.z = f2bf(v.z); o.w = f2bf(v.w);
        *(ushort4*)&tile[rr][c4] = o;
    }
    __syncthreads();
    int ns = tid >> 5, lp = (tid & 31) * 2;
    size_t base = (((size_t)blockIdx.x * 32 + blockIdx.y) * 8 + ns) * 512;
    __align__(16) unsigned short o2[16];
#pragma unroll
    for (int li = 0; li < 2; ++li) {
        int l = lp + li, ul = l & 15, q = (l >> 4) & 3;
#pragma unroll
        for (int j = 0; j < 8; ++j) {
            int kc = (j & 3) + q * 4 + ((j >> 2) << 4);
            o2[li * 8 + j] = tile[kc][ns * 16 + ul];
        }
    }
    *(uint4*)(out + base + lp * 8) = *(const uint4*)&o2[0];
    *(uint4*)(out + base + lp * 8 + 8) = *(const uint4*)&o2[8];
}

__global__ __launch_bounds__(256) void pack_kn(const float* __restrict__ W,
                                               unsigned short* __restrict__ out,
                                               int K, int N, int S)
{
    size_t tid = (size_t)blockIdx.x * 256 + threadIdx.x;
    int l = tid & 63;
    size_t f = tid >> 6;
    int ns = f % S; f /= S;
    int KT = K >> 5;
    int kt = f % KT; int nb = f / KT;
    int n = nb * (16 * S) + ns * 16 + (l & 15);
    int kb = kt * 32 + ((l >> 4) & 3) * 4;
    __align__(16) unsigned short o[8];
#pragma unroll
    for (int j = 0; j < 8; ++j) {
        int k = kb + (j & 3) + ((j >> 2) << 4);
        o[j] = f2bf(W[(size_t)k * N + n]);
    }
    *(uint4*)(out + tid * 8) = *(const uint4*)o;
}

__global__ __launch_bounds__(256) void mean_f(const float* __restrict__ af,
                                              float* __restrict__ fm)
{
    int b = blockIdx.x, tid = threadIdx.x;
    const float* base = af + (size_t)b * kTV * kF;
    float a[8] = {};
    for (int t = 0; t < kTV; ++t) {
        const float* rp = base + (size_t)t * kF + tid * 8;
        float4 v0 = *(const float4*)rp;
        float4 v1 = *(const float4*)(rp + 4);
        a[0] += v0.x; a[1] += v0.y; a[2] += v0.z; a[3] += v0.w;
        a[4] += v1.x; a[5] += v1.y; a[6] += v1.z; a[7] += v1.w;
    }
    float* op = fm + (size_t)b * kF + tid * 8;
#pragma unroll
    for (int j = 0; j < 8; ++j) op[j] = a[j] * (1.f / kTV);
}

__global__ __launch_bounds__(256) void prep_kernel(
    const float* __restrict__ bih1, const float* __restrict__ bhh1,
    const float* __restrict__ bih2, const float* __restrict__ bhh2,
    const float* __restrict__ capmask,
    float* __restrict__ bsum1, float* __restrict__ bsum2, float* __restrict__ msum)
{
    int g = blockIdx.x * 256 + threadIdx.x;
    if (g < 4096) bsum1[g] = bih1[g] + bhh1[g];
    else if (g < 8192) { int j = g - 4096; bsum2[j] = bih2[j] + bhh2[j]; }
    else if (g < 8192 + kNS) {
        int t = g - 8192;
        float s = 0.f;
        for (int b = 0; b < kB; ++b) s += capmask[b * kCAP + t + 1];
        msum[t] = s;
    }
}

template <int KT>
__global__ __launch_bounds__(256) void enc_gemm(
    const unsigned short* __restrict__ Ap, const unsigned short* __restrict__ Bp,
    const float* __restrict__ bias, float* __restrict__ outF)
{
    __shared__ unsigned short Asm[3][2048];
    __shared__ unsigned short Bsm[3][2048];
    int tid = threadIdx.x, w = tid >> 6, l = tid & 63;
    int nb = blockIdx.x, mb = blockIdx.y;
    f32x4 acc[4][1] = {};
    mfma_kloop<1, KT>(Ap + (size_t)mb * KT * 2048, Bp + (size_t)nb * KT * 2048,
                      &Asm[0][0], &Bsm[0][0], w, l, acc);
    int ul = l & 15, sg = l >> 4;
    int n = nb * 64 + w * 16 + ul;
    float bv = bias[n];
#pragma unroll
    for (int ms = 0; ms < 4; ++ms)
#pragma unroll
        for (int r = 0; r < 4; ++r) {
            int row = mb * 64 + ms * 16 + sg * 4 + r;
            outF[(size_t)row * kH + n] = acc[ms][0][r] + bv;
        }
}

__global__ __launch_bounds__(256) void p3_gemm(
    const unsigned short* __restrict__ Ap, const unsigned short* __restrict__ Bp,
    const float* __restrict__ bias, unsigned short* __restrict__ xcat1p,
    unsigned short* __restrict__ h2p)
{
    __shared__ unsigned short Asm[3][2048];
    __shared__ unsigned short Bsm[3][2048];
    int tid = threadIdx.x, w = tid >> 6, l = tid & 63;
    int nb = blockIdx.x;
    f32x4 acc[4][1] = {};
    mfma_kloop<1, 64>(Ap, Bp + (size_t)nb * 64 * 2048, &Asm[0][0], &Bsm[0][0], w, l, acc);
    int ul = l & 15, sg = l >> 4;
    int n = nb * 64 + w * 16 + ul;
    float bv = bias[n];
#pragma unroll
    for (int ms = 0; ms < 4; ++ms)
#pragma unroll
        for (int r = 0; r < 4; ++r) {
            int row = ms * 16 + sg * 4 + r;
            unsigned short hb = f2bf(acc[ms][0][r] + bv);
            store_packedA(xcat1p, row, 2048 + n, hb);
            store_packedA(h2p, row, n, hb);
        }
}

// ---------------- persistent loop kernel ----------------
struct Ctx {
    const unsigned short *W1p, *W2p, *WaP, *WvP;
    unsigned short *x1p, *x2p, *h2p;     // x1p: 2x[64x3072], x2p: 2x[64x2048], h2p: 2x[64x1024]
    float *hw, *c1, *c2;                 // hw: 2x[64x1024]
    const float *bsum1, *bsum2, *imgp, *vf, *attw, *vmask, *Wemb, *embb;
    const int* captions;
    float *psumP, *tlogs;
    int* cnt;                            // [0]=HW [1]=AT [2]=G1 [3]=G2 [4]=LG
};

constexpr int CHW = 0, CAT = 1, CG1 = 2, CG2 = 3, CLG = 4;

__device__ __forceinline__ void gates_body(
    const unsigned short* Ap, const unsigned short* Bp, int nb,
    const float* bsum, float* cbuf,
    unsigned short* dA, int ofsA, unsigned short* dB, int ofsB,
    unsigned short* Asm, unsigned short* Bsm, float* gsm, int KT96)
{
    int tid = threadIdx.x, w = tid >> 6, l = tid & 63;
    f32x4 acc[4][1] = {};
    __syncthreads();
    if (KT96 == 96) mfma_kloop<1, 96>(Ap, Bp, Asm, Bsm, w, l, acc);
    else            mfma_kloop<1, 64>(Ap, Bp, Asm, Bsm, w, l, acc);
    int ul = l & 15, sg = l >> 4;
    float bv = bsum[w * 1024 + nb * 16 + ul];
#pragma unroll
    for (int ms = 0; ms < 4; ++ms)
#pragma unroll
        for (int r = 0; r < 4; ++r)
            gsm[(w * 64 + ms * 16 + sg * 4 + r) * 17 + ul] = acc[ms][0][r] + bv;
    __syncthreads();
#pragma unroll
    for (int q = 0; q < 4; ++q) {
        int idx = tid * 4 + q;
        int row = idx >> 4, uc = idx & 15, u = nb * 16 + uc;
        float gi = gsm[(0 * 64 + row) * 17 + uc], gf = gsm[(1 * 64 + row) * 17 + uc];
        float gg = gsm[(2 * 64 + row) * 17 + uc], go = gsm[(3 * 64 + row) * 17 + uc];
        float c = sigm(gf) * cbuf[(size_t)row * kH + u] + sigm(gi) * tanh_fast(gg);
        cbuf[(size_t)row * kH + u] = c;
        unsigned short hb = f2bf(sigm(go) * tanh_fast(c));
        store_packedA(dA, row, ofsA + u, hb);
        store_packedA(dB, row, ofsB + u, hb);
    }
}

__global__ __launch_bounds__(256) void persist(Ctx c)
{
    __shared__ __align__(16) char smem[57344];
    unsigned short* Asm = (unsigned short*)smem;            // 12 KB (3x2048 us)
    unsigned short* Bsm = (unsigned short*)(smem + 12288);  // 24 KB (3x4096 us max)
    float* gsm = (float*)(smem + 36864);                    // 17.4 KB (chain)
    int bid = blockIdx.x, tid = threadIdx.x;
    int w = tid >> 6, l = tid & 63, ul = l & 15, sg = l >> 4;

    if (bid < 64) {
        // ---------------- chain worker ----------------
        int cb = bid;
        for (int s = 0; s < kNS; ++s) {
            int par = s & 1;
            unsigned short* h2cur = c.h2p + par * 65536;
            unsigned short* x1cur = c.x1p + par * 196608;
            unsigned short* x1nxt = c.x1p + (par ^ 1) * 196608;
            unsigned short* x2cur = c.x2p + par * 131072;
            unsigned short* x2nxt = c.x2p + (par ^ 1) * 131072;
            float* hwcur = c.hw + par * 65536;

            if (cb < 16) {   // hwa(s)
                if (s) waitcnt_dev(c.cnt + CG2, 64 * s);
                f32x4 acc[4][1] = {};
                __syncthreads();
                mfma_kloop<1, 32>(h2cur, c.WaP + (size_t)cb * 32 * 2048,
                                  Asm, Bsm, w, l, acc);
                int n = cb * 64 + w * 16 + ul;
#pragma unroll
                for (int ms = 0; ms < 4; ++ms)
#pragma unroll
                    for (int r = 0; r < 4; ++r)
                        hwcur[(size_t)(ms * 16 + sg * 4 + r) * kH + n] = acc[ms][0][r];
                signal_dev(c.cnt + CHW);
            }
            waitcnt_dev(c.cnt + CHW, 16 * (s + 1));

            {   // attn(s): batch row cb
                int b = cb;
                float* hwv = (float*)smem;
                float* es = (float*)(smem + 4096);
                for (int i = tid; i < kH; i += 256) hwv[i] = hwcur[(size_t)b * kH + i];
                __syncthreads();
                for (int t = w; t < kTV; t += 4) {
                    const float* ip = c.imgp + ((size_t)b * kTV + t) * kH;
                    float p = 0.f;
#pragma unroll
                    for (int hh = 0; hh < 16; ++hh) {
                        int h = hh * 64 + l;
                        p += tanh_fast(hwv[h] + ip[h]) * c.attw[h];
                    }
                    for (int o = 32; o; o >>= 1) p += __shfl_down(p, o);
                    if (l == 0) es[t] = p;
                }
                __syncthreads();
                float mx = -1e30f;
                for (int t = 0; t < kTV; ++t) mx = fmaxf(mx, es[t]);
                const float* vm = c.vmask + b * kTV;
                float den = 0.f;
                for (int t = 0; t < kTV; ++t) den += vm[t] * __expf(es[t] - mx);
                den = den + (den == 0.f ? 1.f : 0.f) + 1e-9f;
                int h0 = tid * 4;
                float4 av = {0.f, 0.f, 0.f, 0.f};
                for (int t = 0; t < kTV; ++t) {
                    float wgt = vm[t] * __expf(es[t] - mx) / den;
                    float4 v = *(const float4*)(c.vf + ((size_t)b * kTV + t) * kH + h0);
                    av.x += wgt * v.x; av.y += wgt * v.y;
                    av.z += wgt * v.z; av.w += wgt * v.w;
                }
                store_packedA(x1cur, b, 1024 + h0 + 0, f2bf(av.x));
                store_packedA(x1cur, b, 1024 + h0 + 1, f2bf(av.y));
                store_packedA(x1cur, b, 1024 + h0 + 2, f2bf(av.z));
                store_packedA(x1cur, b, 1024 + h0 + 3, f2bf(av.w));
                int word = c.captions[b * kCAP + s];
                float4 e4 = *(const float4*)(c.Wemb + (size_t)word * kH + h0);
                store_packedA(x1cur, b, h0 + 0, f2bf(e4.x));
                store_packedA(x1cur, b, h0 + 1, f2bf(e4.y));
                store_packedA(x1cur, b, h0 + 2, f2bf(e4.z));
                store_packedA(x1cur, b, h0 + 3, f2bf(e4.w));
            }
            signal_dev(c.cnt + CAT);
            waitcnt_dev(c.cnt + CAT, 64 * (s + 1));

            gates_body(x1cur, c.W1p + (size_t)cb * 96 * 2048, cb, c.bsum1, c.c1,
                       x1nxt, 2048, x2cur, 0, Asm, Bsm, gsm, 96);
            signal_dev(c.cnt + CG1);
            waitcnt_dev(c.cnt + CG1, 64 * (s + 1));
            if (s >= 2) waitcnt_dev(c.cnt + CLG, 250 * (s - 1));

            gates_body(x2cur, c.W2p + (size_t)cb * 64 * 2048, cb, c.bsum2, c.c2,
                       x2nxt, 1024, c.h2p + (par ^ 1) * 65536, 0, Asm, Bsm, gsm, 64);
            signal_dev(c.cnt + CG2);
        }
    } else {
        // ---------------- logits army ----------------
        int j = bid - 64;
        int* stgt = (int*)(smem + 36864);
        float* rsum = (float*)(smem + 37120);
        for (int s = 0; s < kNS; ++s) {
            waitcnt_dev(c.cnt + CG2, 64 * (s + 1));
            const unsigned short* h2rd = c.h2p + ((s + 1) & 1) * 65536;
            for (int nb = j; nb < 250; nb += 192) {
                if (tid < 64) stgt[tid] = c.captions[tid * kCAP + s + 1];
                f32x4 acc[4][2] = {};
                __syncthreads();
                mfma_kloop<2, 32>(h2rd, c.WvP + (size_t)nb * 32 * 4096,
                                  Asm, Bsm, w, l, acc);
                int n0 = nb * 128 + (2 * w + 0) * 16 + ul;
                int n1 = nb * 128 + (2 * w + 1) * 16 + ul;
                float b0 = c.embb[n0], b1 = c.embb[n1];
                float ls[4][4];
#pragma unroll
                for (int ms = 0; ms < 4; ++ms)
#pragma unroll
                    for (int r = 0; r < 4; ++r) {
                        int row = ms * 16 + sg * 4 + r;
                        float v0 = acc[ms][0][r] + b0, v1 = acc[ms][1][r] + b1;
                        ls[ms][r] = __expf(v0) + __expf(v1);
                        if (n0 == stgt[row]) c.tlogs[s * 64 + row] = v0;
                        if (n1 == stgt[row]) c.tlogs[s * 64 + row] = v1;
                    }
#pragma unroll
                for (int m = 1; m < 16; m <<= 1)
#pragma unroll
                    for (int ms = 0; ms < 4; ++ms)
#pragma unroll
                        for (int r = 0; r < 4; ++r)
                            ls[ms][r] += __shfl_xor(ls[ms][r], m);
                if (ul == 0)
#pragma unroll
                    for (int ms = 0; ms < 4; ++ms)
#pragma unroll
                        for (int r = 0; r < 4; ++r)
                            rsum[w * 64 + ms * 16 + sg * 4 + r] = ls[ms][r];
                __syncthreads();
                if (tid < 64)
                    c.psumP[((size_t)s * 250 + nb) * 64 + tid] =
                        rsum[0 * 64 + tid] + rsum[1 * 64 + tid] +
                        rsum[2 * 64 + tid] + rsum[3 * 64 + tid];
                signal_dev(c.cnt + CLG);
            }
        }
    }
}

// ---------------- final loss over all steps ----------------
__global__ __launch_bounds__(256) void final_loss(
    const float* __restrict__ psumP, const float* __restrict__ tlogs,
    const float* __restrict__ msum, float* __restrict__ out)
{
    __shared__ float sl[16000];
    int s = blockIdx.x, tid = threadIdx.x;
    const float* src = psumP + (size_t)s * 16000;
    for (int i = tid; i < 16000; i += 256) sl[i] = src[i];
    __syncthreads();
    if (tid < 64) {
        float tot = 0.f;
        for (int i = 0; i < 250; ++i) tot += sl[i * 64 + tid];
        float logp = tlogs[s * 64 + tid] - __logf(tot);
        float term = -logp * msum[s] * (1.f / 4096.f);
        for (int off = 32; off; off >>= 1) term += __shfl_down(term, off);
        if (tid == 0) atomicAdd(out, term);
    }
}

// ---------------- host ----------------
extern "C" void kernel_launch(void* const* d_in, const int* in_sizes, int n_in,
                              void* d_out, int out_size, void* d_ws, size_t ws_size,
                              hipStream_t stream)
{
    const float* action_feat = (const float*)d_in[1];
    const float* video_mask  = (const float*)d_in[3];
    const int*   captions    = (const int*)d_in[4];
    const float* capmask     = (const float*)d_in[5];
    const float* enc_img_W   = (const float*)d_in[6];
    const float* enc_img_b   = (const float*)d_in[7];
    const float* enc_mean_W  = (const float*)d_in[8];
    const float* enc_mean_b  = (const float*)d_in[9];
    const float* att_w       = (const float*)d_in[10];
    const float* att_Wa      = (const float*)d_in[11];
    const float* att_Ua      = (const float*)d_in[12];
    const float* att_ba      = (const float*)d_in[13];
    const float* Wemb        = (const float*)d_in[14];
    const float* embW        = (const float*)d_in[15];
    const float* embb        = (const float*)d_in[16];
    const float* W1ih        = (const float*)d_in[17];
    const float* W1hh        = (const float*)d_in[18];
    const float* b1ih        = (const float*)d_in[19];
    const float* b1hh        = (const float*)d_in[20];
    const float* W2ih        = (const float*)d_in[21];
    const float* W2hh        = (const float*)d_in[22];
    const float* b2ih        = (const float*)d_in[23];
    const float* b2hh        = (const float*)d_in[24];

    char* base = (char*)d_ws;
    size_t off = 0;
    auto alloc = [&](size_t bytes) {
        char* p = base + off;
        off = (off + bytes + 255) & ~(size_t)255;
        return p;
    };
    constexpr int BIG = 0x40000000;

    float* vf    = (float*)alloc((size_t)2560 * 1024 * 4);
    float* imgp  = (float*)alloc((size_t)2560 * 1024 * 4);
    float* fm    = (float*)alloc((size_t)64 * 2048 * 4);
    float* hw    = (float*)alloc((size_t)2 * 64 * 1024 * 4);
    float* bsum1 = (float*)alloc(4096 * 4);
    float* bsum2 = (float*)alloc(4096 * 4);
    float* msum  = (float*)alloc(32 * 4);
    float* psumP = (float*)alloc((size_t)kNS * 250 * 64 * 4);
    float* tlogs = (float*)alloc((size_t)kNS * 64 * 4);
    // zero-init block: counters, x2p[2], c1, c2 (contiguous)
    int* cnts    = (int*)alloc(256);
    unsigned short* x2p = (unsigned short*)alloc((size_t)2 * 64 * 2048 * 2);
    float* c1    = (float*)alloc((size_t)64 * 1024 * 4);
    float* c2    = (float*)alloc((size_t)64 * 1024 * 4);
    size_t zlen  = (size_t)((char*)(c2 + 64 * 1024) - (char*)cnts);

    unsigned short* x1p  = (unsigned short*)alloc((size_t)2 * 64 * 3072 * 2);
    unsigned short* h2p  = (unsigned short*)alloc((size_t)2 * 64 * 1024 * 2);
    unsigned short* afP  = (unsigned short*)alloc((size_t)2560 * 2048 * 2);
    unsigned short* vfP  = (unsigned short*)alloc((size_t)2560 * 1024 * 2);
    unsigned short* fmP  = (unsigned short*)alloc((size_t)64 * 2048 * 2);
    unsigned short* WiP  = (unsigned short*)alloc((size_t)2048 * 1024 * 2);
    unsigned short* WmP  = (unsigned short*)alloc((size_t)2048 * 1024 * 2);
    unsigned short* WuaP = (unsigned short*)alloc((size_t)1024 * 1024 * 2);
    unsigned short* WaP  = (unsigned short*)alloc((size_t)1024 * 1024 * 2);
    unsigned short* W1p  = (unsigned short*)alloc((size_t)3072 * 4096 * 2);
    unsigned short* W2p  = (unsigned short*)alloc((size_t)2048 * 4096 * 2);
    unsigned short* WvP  = (unsigned short*)alloc((size_t)1024 * 32000 * 2);
    if (off > ws_size) return;

    hipMemsetAsync(d_out, 0, 4, stream);
    hipMemsetAsync(cnts, 0, zlen, stream);

    prep_kernel<<<33, 256, 0, stream>>>(b1ih, b1hh, b2ih, b2hh, capmask,
                                        bsum1, bsum2, msum);
    mean_f<<<64, 256, 0, stream>>>(action_feat, fm);
    pack_rm<<<dim3(16, 4), 256, 0, stream>>>(fm, 2048, BIG, nullptr, 0,
                                             4, 16, 64, 64, fmP);
    pack_rm<<<dim3(16, 160), 256, 0, stream>>>(action_feat, 2048, BIG, nullptr, 0,
                                               4, 16, 64, 64, afP);
    pack_rm<<<dim3(24, 256), 256, 0, stream>>>(W1ih, 2048, 2048, W1hh, 1024,
                                               4, 1024, 16, 96, W1p);
    pack_rm<<<dim3(16, 256), 256, 0, stream>>>(W2ih, 1024, 1024, W2hh, 1024,
                                               4, 1024, 16, 64, W2p);
    pack_kn<<<1024, 256, 0, stream>>>(enc_img_W, WiP, 2048, 1024, 4);
    pack_kn<<<1024, 256, 0, stream>>>(enc_mean_W, WmP, 2048, 1024, 4);
    pack_kn<<<512, 256, 0, stream>>>(att_Ua, WuaP, 1024, 1024, 4);
    pack_kn<<<512, 256, 0, stream>>>(att_Wa, WaP, 1024, 1024, 4);
    pack_cm<<<dim3(250, 32), 256, 0, stream>>>(embW, WvP);

    enc_gemm<64><<<dim3(16, 40), 256, 0, stream>>>(afP, WiP, enc_img_b, vf);
    pack_rm<<<dim3(8, 160), 256, 0, stream>>>(vf, 1024, BIG, nullptr, 0,
                                              4, 16, 64, 32, vfP);
    p3_gemm<<<16, 256, 0, stream>>>(fmP, WmP, enc_mean_b, x1p, h2p);
    enc_gemm<32><<<dim3(16, 40), 256, 0, stream>>>(vfP, WuaP, att_ba, imgp);

    Ctx c;
    c.W1p = W1p; c.W2p = W2p; c.WaP = WaP; c.WvP = WvP;
    c.x1p = x1p; c.x2p = x2p; c.h2p = h2p;
    c.hw = hw; c.c1 = c1; c.c2 = c2;
    c.bsum1 = bsum1; c.bsum2 = bsum2; c.imgp = imgp; c.vf = vf;
    c.attw = att_w; c.vmask = video_mask; c.Wemb = Wemb; c.embb = embb;
    c.captions = captions; c.psumP = psumP; c.tlogs = tlogs; c.cnt = cnts;
    persist<<<256, 256, 0, stream>>>(c);

    final_loss<<<kNS, 256, 0, stream>>>(psumP, tlogs, msum, (float*)d_out);
}

// Round 5
// 2412.019 us; speedup vs baseline: 3.7157x; 3.7157x over previous
//
#include <hip/hip_runtime.h>
#include <stdint.h>

constexpr int kB   = 64;
constexpr int kTV  = 40;
constexpr int kF   = 2048;
constexpr int kH   = 1024;
constexpr int kV   = 32000;
constexpr int kNS  = 30;
constexpr int kCAP = 31;

typedef __attribute__((ext_vector_type(8))) short bf16x8;
typedef __attribute__((ext_vector_type(4))) float f32x4;

__device__ __forceinline__ float sigm(float x) { return 1.f / (1.f + __expf(-x)); }
__device__ __forceinline__ float tanh_fast(float x) {
    float e = __expf(2.f * x);
    return 1.f - 2.f / (e + 1.f);
}
__device__ __forceinline__ unsigned short f2bf(float x) {
    unsigned u = __float_as_uint(x);
    return (unsigned short)((u + 0x7fffu + ((u >> 16) & 1u)) >> 16);
}

__device__ __forceinline__ void gl16(const unsigned short* g, unsigned short* lds) {
    __builtin_amdgcn_global_load_lds(
        (const __attribute__((address_space(1))) unsigned int*)(g),
        (__attribute__((address_space(3))) unsigned int*)(lds), 16, 0, 0);
}

template <int N>
__device__ __forceinline__ void waitv() {
    asm volatile("s_waitcnt vmcnt(%0)" :: "n"(N) : "memory");
}
__device__ __forceinline__ void barrier_raw() {
    __builtin_amdgcn_s_barrier();
    asm volatile("" ::: "memory");
}

// A-packed layout: [kt][ms][lane][j]; (row,col): ms=row>>4,
// lane=(row&15)+16*((kc>>2)&3), j=(kc&3)+4*(kc>>4), kc=col&31, kt=col>>5.
__device__ __forceinline__ void store_packedA(unsigned short* base, int row, int col,
                                              unsigned short v) {
    int kt = col >> 5, kc = col & 31, ms = row >> 4;
    int l = (row & 15) + (((kc >> 2) & 3) << 4);
    int j = (kc & 3) + ((kc >> 4) << 2);
    base[((((size_t)kt * 4 + ms) * 64 + l) << 3) + j] = v;
}

// ---------------- 3-deep pipelined MFMA K-loop (4 waves, w in [0,4)) ----------------
template <int NSPW, int KT>
__device__ __forceinline__ void mfma_kloop(
    const unsigned short* __restrict__ Ap, const unsigned short* __restrict__ Bp,
    unsigned short* Asm, unsigned short* Bsm, int w, int l, f32x4 acc[4][NSPW])
{
    constexpr int BSTEP = 2048 * NSPW;
    constexpr int LPT = 1 + NSPW;
    auto stage = [&](int t, int slot) {
        gl16(Ap + (size_t)t * 2048 + w * 512 + l * 8, Asm + slot * 2048 + w * 512);
#pragma unroll
        for (int i = 0; i < NSPW; ++i)
            gl16(Bp + (size_t)t * BSTEP + (w * NSPW + i) * 512 + l * 8,
                 Bsm + slot * BSTEP + (w * NSPW + i) * 512);
    };
    stage(0, 0); stage(1, 1); stage(2, 2);
#pragma unroll 1
    for (int t = 0; t < KT; ++t) {
        int slot = t % 3;
        int rem = KT - 1 - t;
        if (rem >= 2) waitv<2 * LPT>();
        else if (rem == 1) waitv<LPT>();
        else waitv<0>();
        barrier_raw();
        bf16x8 bfr[NSPW], afr[4];
#pragma unroll
        for (int i = 0; i < NSPW; ++i)
            bfr[i] = *(const bf16x8*)(Bsm + slot * BSTEP + ((w * NSPW + i) * 64 + l) * 8);
#pragma unroll
        for (int ms = 0; ms < 4; ++ms)
            afr[ms] = *(const bf16x8*)(Asm + slot * 2048 + (ms * 64 + l) * 8);
#pragma unroll
        for (int ms = 0; ms < 4; ++ms)
#pragma unroll
            for (int i = 0; i < NSPW; ++i)
                acc[ms][i] = __builtin_amdgcn_mfma_f32_16x16x32_bf16(
                    afr[ms], bfr[i], acc[ms][i], 0, 0, 0);
        __builtin_amdgcn_sched_barrier(0);
        barrier_raw();
        if (t + 3 < KT) stage(t + 3, slot);
    }
}

// ---------------- packing kernels (setup) ----------------
__global__ __launch_bounds__(256) void pack_rm(
    const float* __restrict__ p0, int ld0, int ksplit,
    const float* __restrict__ p1, int ld1,
    int NGRP, int GS, int HS, int KT,
    unsigned short* __restrict__ out)
{
    __shared__ unsigned short tile[16][136];
    int kb = blockIdx.x * 128;
    int grp = blockIdx.y;
    int row0 = (grp % NGRP) * GS + (grp / NGRP) * HS;
    int tid = threadIdx.x;
    int r = tid >> 5, c4 = (tid & 31) * 4;
#pragma unroll
    for (int pass = 0; pass < 2; ++pass) {
        int rr = r + pass * 8;
        int row = row0 + rr;
        int k = kb + c4;
        float4 v;
        if (k < ksplit) v = *(const float4*)(p0 + (size_t)row * ld0 + k);
        else            v = *(const float4*)(p1 + (size_t)row * ld1 + (k - ksplit));
        ushort4 o; o.x = f2bf(v.x); o.y = f2bf(v.y); o.z = f2bf(v.z); o.w = f2bf(v.w);
        *(ushort4*)&tile[rr][c4] = o;
    }
    __syncthreads();
    int ktl = tid >> 6, l = tid & 63, ul = l & 15, q = (l >> 4) & 3;
    __align__(16) unsigned short o2[8];
#pragma unroll
    for (int j = 0; j < 8; ++j) {
        int kc = (j & 3) + q * 4 + ((j >> 2) << 4);
        o2[j] = tile[ul][ktl * 32 + kc];
    }
    int kt = (kb >> 5) + ktl;
    size_t base = (((size_t)(grp / NGRP) * KT + kt) * NGRP + (grp % NGRP)) * 512;
    *(uint4*)(out + base + (size_t)l * 8) = *(const uint4*)o2;
}

__global__ __launch_bounds__(256) void pack_cm(const float* __restrict__ W,
                                               unsigned short* __restrict__ out)
{
    __shared__ unsigned short tile[32][136];
    int n0 = blockIdx.x * 128, k0 = blockIdx.y * 32;
    int tid = threadIdx.x;
    int r = tid >> 5, c4 = (tid & 31) * 4;
#pragma unroll
    for (int pass = 0; pass < 4; ++pass) {
        int rr = r + pass * 8;
        float4 v = *(const float4*)(W + (size_t)(k0 + rr) * kV + n0 + c4);
        ushort4 o; o.x = f2bf(v.x); o.y = f2bf(v.y); o.z = f2bf(v.z); o.w = f2bf(v.w);
        *(ushort4*)&tile[rr][c4] = o;
    }
    __syncthreads();
    int ns = tid >> 5, lp = (tid & 31) * 2;
    size_t base = (((size_t)blockIdx.x * 32 + blockIdx.y) * 8 + ns) * 512;
    __align__(16) unsigned short o2[16];
#pragma unroll
    for (int li = 0; li < 2; ++li) {
        int l = lp + li, ul = l & 15, q = (l >> 4) & 3;
#pragma unroll
        for (int j = 0; j < 8; ++j) {
            int kc = (j & 3) + q * 4 + ((j >> 2) << 4);
            o2[li * 8 + j] = tile[kc][ns * 16 + ul];
        }
    }
    *(uint4*)(out + base + lp * 8) = *(const uint4*)&o2[0];
    *(uint4*)(out + base + lp * 8 + 8) = *(const uint4*)&o2[8];
}

// 4 small [K][1024] weights -> B-tiles (S=4), merged into one dispatch
__global__ __launch_bounds__(256) void pack_kn4(
    const float* __restrict__ Wi, const float* __restrict__ Wm,
    const float* __restrict__ Wua, const float* __restrict__ Wa,
    unsigned short* __restrict__ oi, unsigned short* __restrict__ om,
    unsigned short* __restrict__ oua, unsigned short* __restrict__ oa)
{
    int bid = blockIdx.x;
    const float* W; unsigned short* out; int K, rel;
    if (bid < 1024)       { W = Wi;  out = oi;  K = 2048; rel = bid; }
    else if (bid < 2048)  { W = Wm;  out = om;  K = 2048; rel = bid - 1024; }
    else if (bid < 2560)  { W = Wua; out = oua; K = 1024; rel = bid - 2048; }
    else                  { W = Wa;  out = oa;  K = 1024; rel = bid - 2560; }
    size_t tid = (size_t)rel * 256 + threadIdx.x;
    int l = tid & 63;
    size_t f = tid >> 6;
    int ns = f & 3; f >>= 2;
    int KT = K >> 5;
    int kt = f % KT; int nb = f / KT;
    int n = nb * 64 + ns * 16 + (l & 15);
    int kb = kt * 32 + ((l >> 4) & 3) * 4;
    __align__(16) unsigned short o[8];
#pragma unroll
    for (int j = 0; j < 8; ++j) {
        int k = kb + (j & 3) + ((j >> 2) << 4);
        o[j] = f2bf(W[(size_t)k * 1024 + n]);
    }
    *(uint4*)(out + tid * 8) = *(const uint4*)o;
}

// mean_f (blocks 0..63) + bias/mask prep (blocks 64..96) merged
__global__ __launch_bounds__(256) void prep_mean(
    const float* __restrict__ af, float* __restrict__ fm,
    const float* __restrict__ bih1, const float* __restrict__ bhh1,
    const float* __restrict__ bih2, const float* __restrict__ bhh2,
    const float* __restrict__ capmask,
    float* __restrict__ bsum1, float* __restrict__ bsum2, float* __restrict__ msum)
{
    int tid = threadIdx.x;
    if (blockIdx.x < 64) {
        int b = blockIdx.x;
        const float* base = af + (size_t)b * kTV * kF;
        float a[8] = {};
        for (int t = 0; t < kTV; ++t) {
            const float* rp = base + (size_t)t * kF + tid * 8;
            float4 v0 = *(const float4*)rp;
            float4 v1 = *(const float4*)(rp + 4);
            a[0] += v0.x; a[1] += v0.y; a[2] += v0.z; a[3] += v0.w;
            a[4] += v1.x; a[5] += v1.y; a[6] += v1.z; a[7] += v1.w;
        }
        float* op = fm + (size_t)b * kF + tid * 8;
#pragma unroll
        for (int j = 0; j < 8; ++j) op[j] = a[j] * (1.f / kTV);
    } else {
        int g = (blockIdx.x - 64) * 256 + tid;
        if (g < 4096) bsum1[g] = bih1[g] + bhh1[g];
        else if (g < 8192) { int j = g - 4096; bsum2[j] = bih2[j] + bhh2[j]; }
        else if (g < 8192 + kNS) {
            int t = g - 8192;
            float s = 0.f;
            for (int b = 0; b < kB; ++b) s += capmask[b * kCAP + t + 1];
            msum[t] = s;
        }
    }
}

// ---------------- encoder GEMM: outF = A@B + bias (+optional packed copy) ----------------
template <int KT>
__global__ __launch_bounds__(256) void enc_gemm(
    const unsigned short* __restrict__ Ap, const unsigned short* __restrict__ Bp,
    const float* __restrict__ bias, float* __restrict__ outF,
    unsigned short* __restrict__ outP)
{
    __shared__ unsigned short Asm[3][2048];
    __shared__ unsigned short Bsm[3][2048];
    int tid = threadIdx.x, w = tid >> 6, l = tid & 63;
    int nb = blockIdx.x, mb = blockIdx.y;
    f32x4 acc[4][1] = {};
    mfma_kloop<1, KT>(Ap + (size_t)mb * KT * 2048, Bp + (size_t)nb * KT * 2048,
                      &Asm[0][0], &Bsm[0][0], w, l, acc);
    int ul = l & 15, sg = l >> 4;
    int n = nb * 64 + w * 16 + ul;
    float bv = bias[n];
#pragma unroll
    for (int ms = 0; ms < 4; ++ms)
#pragma unroll
        for (int r = 0; r < 4; ++r) {
            int rl = ms * 16 + sg * 4 + r;
            int row = mb * 64 + rl;
            float v = acc[ms][0][r] + bv;
            outF[(size_t)row * kH + n] = v;
            if (outP) store_packedA(outP + (size_t)mb * 65536, rl, n, f2bf(v));
        }
}

__global__ __launch_bounds__(256) void p3_gemm(
    const unsigned short* __restrict__ Ap, const unsigned short* __restrict__ Bp,
    const float* __restrict__ bias, unsigned short* __restrict__ xcat1p,
    unsigned short* __restrict__ h2p)
{
    __shared__ unsigned short Asm[3][2048];
    __shared__ unsigned short Bsm[3][2048];
    int tid = threadIdx.x, w = tid >> 6, l = tid & 63;
    int nb = blockIdx.x;
    f32x4 acc[4][1] = {};
    mfma_kloop<1, 64>(Ap, Bp + (size_t)nb * 64 * 2048, &Asm[0][0], &Bsm[0][0], w, l, acc);
    int ul = l & 15, sg = l >> 4;
    int n = nb * 64 + w * 16 + ul;
    float bv = bias[n];
#pragma unroll
    for (int ms = 0; ms < 4; ++ms)
#pragma unroll
        for (int r = 0; r < 4; ++r) {
            int row = ms * 16 + sg * 4 + r;
            unsigned short hb = f2bf(acc[ms][0][r] + bv);
            store_packedA(xcat1p, row, 2048 + n, hb);
            store_packedA(h2p, row, n, hb);
        }
}

// ---------------- AL kernel: hwa(s+1) [blocks < nHwa] + logits(s) [rest] ----------------
__global__ __launch_bounds__(256) void al_kernel(
    const unsigned short* __restrict__ h2p, const unsigned short* __restrict__ WaP,
    float* __restrict__ hw,
    const unsigned short* __restrict__ WvP, const float* __restrict__ embb,
    const int* __restrict__ captions, int sLog,
    float* __restrict__ psumP, float* __restrict__ tlogs, int nHwa)
{
    __shared__ unsigned short Asm[3][2048];
    __shared__ unsigned short Bsm2[3][4096];
    __shared__ float rsum[4][64];
    __shared__ int stgt[64];
    int tid = threadIdx.x, w = tid >> 6, l = tid & 63;
    int ul = l & 15, sg = l >> 4;
    if (blockIdx.x < nHwa) {
        int nb = blockIdx.x;
        f32x4 acc[4][1] = {};
        mfma_kloop<1, 32>(h2p, WaP + (size_t)nb * 32 * 2048,
                          &Asm[0][0], &Bsm2[0][0], w, l, acc);
        int n = nb * 64 + w * 16 + ul;
#pragma unroll
        for (int ms = 0; ms < 4; ++ms)
#pragma unroll
            for (int r = 0; r < 4; ++r)
                hw[(size_t)(ms * 16 + sg * 4 + r) * kH + n] = acc[ms][0][r];
    } else {
        int nb = blockIdx.x - nHwa;
        if (tid < 64) stgt[tid] = captions[tid * kCAP + sLog + 1];
        f32x4 acc[4][2] = {};
        mfma_kloop<2, 32>(h2p, WvP + (size_t)nb * 32 * 4096,
                          &Asm[0][0], &Bsm2[0][0], w, l, acc);
        int n0 = nb * 128 + (2 * w + 0) * 16 + ul;
        int n1 = nb * 128 + (2 * w + 1) * 16 + ul;
        float b0 = embb[n0], b1 = embb[n1];
        float ls[4][4];
#pragma unroll
        for (int ms = 0; ms < 4; ++ms)
#pragma unroll
            for (int r = 0; r < 4; ++r) {
                int row = ms * 16 + sg * 4 + r;
                float v0 = acc[ms][0][r] + b0, v1 = acc[ms][1][r] + b1;
                ls[ms][r] = __expf(v0) + __expf(v1);
                if (n0 == stgt[row]) tlogs[sLog * 64 + row] = v0;
                if (n1 == stgt[row]) tlogs[sLog * 64 + row] = v1;
            }
#pragma unroll
        for (int m = 1; m < 16; m <<= 1)
#pragma unroll
            for (int ms = 0; ms < 4; ++ms)
#pragma unroll
                for (int r = 0; r < 4; ++r)
                    ls[ms][r] += __shfl_xor(ls[ms][r], m);
        if (ul == 0)
#pragma unroll
            for (int ms = 0; ms < 4; ++ms)
#pragma unroll
                for (int r = 0; r < 4; ++r)
                    rsum[w][ms * 16 + sg * 4 + r] = ls[ms][r];
        __syncthreads();
        if (tid < 64)
            psumP[((size_t)sLog * 250 + nb) * 64 + tid] =
                rsum[0][tid] + rsum[1][tid] + rsum[2][tid] + rsum[3][tid];
    }
}

// ---------------- fused attention (per batch row) ----------------
__global__ __launch_bounds__(256) void attn_fused(
    const float* __restrict__ hw, const float* __restrict__ imgp,
    const float* __restrict__ attw, const float* __restrict__ vf,
    const float* __restrict__ vmask, const float* __restrict__ Wemb,
    const int* __restrict__ captions, int s, unsigned short* __restrict__ xcat1p)
{
    __shared__ float hwv[kH];
    __shared__ float es[48];
    int b = blockIdx.x, tid = threadIdx.x;
    for (int i = tid; i < kH; i += 256) hwv[i] = hw[(size_t)b * kH + i];
    __syncthreads();
    int w = tid >> 6, l = tid & 63;
    for (int t = w; t < kTV; t += 4) {
        const float* ip = imgp + ((size_t)b * kTV + t) * kH;
        float p = 0.f;
#pragma unroll
        for (int hh = 0; hh < 16; ++hh) {
            int h = hh * 64 + l;
            p += tanh_fast(hwv[h] + ip[h]) * attw[h];
        }
        for (int off = 32; off; off >>= 1) p += __shfl_down(p, off);
        if (l == 0) es[t] = p;
    }
    __syncthreads();
    float mx = -1e30f;
    for (int t = 0; t < kTV; ++t) mx = fmaxf(mx, es[t]);
    const float* vm = vmask + b * kTV;
    float den = 0.f;
    for (int t = 0; t < kTV; ++t) den += vm[t] * __expf(es[t] - mx);
    den = den + (den == 0.f ? 1.f : 0.f) + 1e-9f;
    int h0 = tid * 4;
    float4 av = {0.f, 0.f, 0.f, 0.f};
    for (int t = 0; t < kTV; ++t) {
        float wgt = vm[t] * __expf(es[t] - mx) / den;
        float4 v = *(const float4*)(vf + ((size_t)b * kTV + t) * kH + h0);
        av.x += wgt * v.x; av.y += wgt * v.y; av.z += wgt * v.z; av.w += wgt * v.w;
    }
    store_packedA(xcat1p, b, 1024 + h0 + 0, f2bf(av.x));
    store_packedA(xcat1p, b, 1024 + h0 + 1, f2bf(av.y));
    store_packedA(xcat1p, b, 1024 + h0 + 2, f2bf(av.z));
    store_packedA(xcat1p, b, 1024 + h0 + 3, f2bf(av.w));
    int word = captions[b * kCAP + s];
    float4 e4 = *(const float4*)(Wemb + (size_t)word * kH + h0);
    store_packedA(xcat1p, b, h0 + 0, f2bf(e4.x));
    store_packedA(xcat1p, b, h0 + 1, f2bf(e4.y));
    store_packedA(xcat1p, b, h0 + 2, f2bf(e4.z));
    store_packedA(xcat1p, b, h0 + 3, f2bf(e4.w));
}

// ---------------- gates GEMM + fused LSTM cell (512 thr, in-block K-split) ----------------
template <int KT>
__global__ __launch_bounds__(512) void gates_cell(
    const unsigned short* __restrict__ Ap, const unsigned short* __restrict__ Bp,
    const float* __restrict__ bsum, float* __restrict__ cbuf,
    unsigned short* __restrict__ dA, int ofsA,
    unsigned short* __restrict__ dB, int ofsB)
{
    __shared__ __align__(16) char smem[49152];
    unsigned short* Asm = (unsigned short*)smem;           // 2 halves x 3 x 2048 us
    unsigned short* Bsm = (unsigned short*)(smem + 24576);
    float* gsm = (float*)smem;                             // aliased after kloop
    constexpr int KH = KT / 2;
    int tid = threadIdx.x, w = tid >> 6, l = tid & 63, nb = blockIdx.x;
    int h = w >> 2, w4 = w & 3;
    f32x4 acc[4][1] = {};
    mfma_kloop<1, KH>(Ap + (size_t)h * KH * 2048,
                      Bp + (size_t)nb * KT * 2048 + (size_t)h * KH * 2048,
                      Asm + h * 6144, Bsm + h * 6144, w4, l, acc);
    int ul = l & 15, sg = l >> 4;
    float bv = (h == 0) ? bsum[w4 * 1024 + nb * 16 + ul] : 0.f;
    __syncthreads();   // all LDS reads of kloop done before gsm aliasing
#pragma unroll
    for (int ms = 0; ms < 4; ++ms)
#pragma unroll
        for (int r = 0; r < 4; ++r)
            gsm[(((h * 4 + w4) * 64) + ms * 16 + sg * 4 + r) * 17 + ul] =
                acc[ms][0][r] + bv;
    __syncthreads();
#pragma unroll
    for (int q = 0; q < 2; ++q) {
        int idx = tid * 2 + q;
        int row = idx >> 4, uc = idx & 15, u = nb * 16 + uc;
        float gi = gsm[((0 * 64) + row) * 17 + uc] + gsm[((4 * 64) + row) * 17 + uc];
        float gf = gsm[((1 * 64) + row) * 17 + uc] + gsm[((5 * 64) + row) * 17 + uc];
        float gg = gsm[((2 * 64) + row) * 17 + uc] + gsm[((6 * 64) + row) * 17 + uc];
        float go = gsm[((3 * 64) + row) * 17 + uc] + gsm[((7 * 64) + row) * 17 + uc];
        float c = sigm(gf) * cbuf[(size_t)row * kH + u] + sigm(gi) * tanh_fast(gg);
        cbuf[(size_t)row * kH + u] = c;
        unsigned short hb = f2bf(sigm(go) * tanh_fast(c));
        store_packedA(dA, row, ofsA + u, hb);
        store_packedA(dB, row, ofsB + u, hb);
    }
}

// ---------------- final loss over all steps ----------------
__global__ __launch_bounds__(256) void final_loss(
    const float* __restrict__ psumP, const float* __restrict__ tlogs,
    const float* __restrict__ msum, float* __restrict__ out)
{
    __shared__ float sl[16000];
    int s = blockIdx.x, tid = threadIdx.x;
    const float* src = psumP + (size_t)s * 16000;
    for (int i = tid; i < 16000; i += 256) sl[i] = src[i];
    __syncthreads();
    if (tid < 64) {
        float tot = 0.f;
        for (int i = 0; i < 250; ++i) tot += sl[i * 64 + tid];
        float logp = tlogs[s * 64 + tid] - __logf(tot);
        float term = -logp * msum[s] * (1.f / 4096.f);
        for (int off = 32; off; off >>= 1) term += __shfl_down(term, off);
        if (tid == 0) atomicAdd(out, term);
    }
}

// ---------------- host ----------------
extern "C" void kernel_launch(void* const* d_in, const int* in_sizes, int n_in,
                              void* d_out, int out_size, void* d_ws, size_t ws_size,
                              hipStream_t stream)
{
    const float* action_feat = (const float*)d_in[1];
    const float* video_mask  = (const float*)d_in[3];
    const int*   captions    = (const int*)d_in[4];
    const float* capmask     = (const float*)d_in[5];
    const float* enc_img_W   = (const float*)d_in[6];
    const float* enc_img_b   = (const float*)d_in[7];
    const float* enc_mean_W  = (const float*)d_in[8];
    const float* enc_mean_b  = (const float*)d_in[9];
    const float* att_w       = (const float*)d_in[10];
    const float* att_Wa      = (const float*)d_in[11];
    const float* att_Ua      = (const float*)d_in[12];
    const float* att_ba      = (const float*)d_in[13];
    const float* Wemb        = (const float*)d_in[14];
    const float* embW        = (const float*)d_in[15];
    const float* embb        = (const float*)d_in[16];
    const float* W1ih        = (const float*)d_in[17];
    const float* W1hh        = (const float*)d_in[18];
    const float* b1ih        = (const float*)d_in[19];
    const float* b1hh        = (const float*)d_in[20];
    const float* W2ih        = (const float*)d_in[21];
    const float* W2hh        = (const float*)d_in[22];
    const float* b2ih        = (const float*)d_in[23];
    const float* b2hh        = (const float*)d_in[24];

    char* base = (char*)d_ws;
    size_t off = 0;
    auto alloc = [&](size_t bytes) {
        char* p = base + off;
        off = (off + bytes + 255) & ~(size_t)255;
        return p;
    };
    constexpr int BIG = 0x40000000;

    float* vf    = (float*)alloc((size_t)2560 * 1024 * 4);
    float* imgp  = (float*)alloc((size_t)2560 * 1024 * 4);
    float* fm    = (float*)alloc((size_t)64 * 2048 * 4);
    float* hw    = (float*)alloc((size_t)64 * 1024 * 4);
    float* bsum1 = (float*)alloc(4096 * 4);
    float* bsum2 = (float*)alloc(4096 * 4);
    float* msum  = (float*)alloc(32 * 4);
    float* psumP = (float*)alloc((size_t)kNS * 250 * 64 * 4);
    float* tlogs = (float*)alloc((size_t)kNS * 64 * 4);
    // zero-init block: x2p[2], c1, c2 contiguous
    unsigned short* x2p0 = (unsigned short*)alloc((size_t)64 * 2048 * 2);
    unsigned short* x2p1 = (unsigned short*)alloc((size_t)64 * 2048 * 2);
    float* c1    = (float*)alloc((size_t)64 * 1024 * 4);
    float* c2    = (float*)alloc((size_t)64 * 1024 * 4);
    size_t zlen  = (size_t)((char*)(c2 + 64 * 1024) - (char*)x2p0);

    unsigned short* x1p0 = (unsigned short*)alloc((size_t)64 * 3072 * 2);
    unsigned short* x1p1 = (unsigned short*)alloc((size_t)64 * 3072 * 2);
    unsigned short* h2p  = (unsigned short*)alloc((size_t)64 * 1024 * 2);
    unsigned short* afP  = (unsigned short*)alloc((size_t)2560 * 2048 * 2);
    unsigned short* vfP  = (unsigned short*)alloc((size_t)2560 * 1024 * 2);
    unsigned short* fmP  = (unsigned short*)alloc((size_t)64 * 2048 * 2);
    unsigned short* WiP  = (unsigned short*)alloc((size_t)2048 * 1024 * 2);
    unsigned short* WmP  = (unsigned short*)alloc((size_t)2048 * 1024 * 2);
    unsigned short* WuaP = (unsigned short*)alloc((size_t)1024 * 1024 * 2);
    unsigned short* WaP  = (unsigned short*)alloc((size_t)1024 * 1024 * 2);
    unsigned short* W1p  = (unsigned short*)alloc((size_t)3072 * 4096 * 2);
    unsigned short* W2p  = (unsigned short*)alloc((size_t)2048 * 4096 * 2);
    unsigned short* WvP  = (unsigned short*)alloc((size_t)1024 * 32000 * 2);
    if (off > ws_size) return;

    hipMemsetAsync(d_out, 0, 4, stream);
    hipMemsetAsync(x2p0, 0, zlen, stream);

    prep_mean<<<97, 256, 0, stream>>>(action_feat, fm, b1ih, b1hh, b2ih, b2hh,
                                      capmask, bsum1, bsum2, msum);
    pack_rm<<<dim3(16, 4), 256, 0, stream>>>(fm, 2048, BIG, nullptr, 0,
                                             4, 16, 64, 64, fmP);
    pack_rm<<<dim3(16, 160), 256, 0, stream>>>(action_feat, 2048, BIG, nullptr, 0,
                                               4, 16, 64, 64, afP);
    pack_rm<<<dim3(24, 256), 256, 0, stream>>>(W1ih, 2048, 2048, W1hh, 1024,
                                               4, 1024, 16, 96, W1p);
    pack_rm<<<dim3(16, 256), 256, 0, stream>>>(W2ih, 1024, 1024, W2hh, 1024,
                                               4, 1024, 16, 64, W2p);
    pack_kn4<<<3072, 256, 0, stream>>>(enc_img_W, enc_mean_W, att_Ua, att_Wa,
                                       WiP, WmP, WuaP, WaP);
    pack_cm<<<dim3(250, 32), 256, 0, stream>>>(embW, WvP);

    // P1: vf = af @ enc_img_W + b (also writes packed vfP); P3; P4
    enc_gemm<64><<<dim3(16, 40), 256, 0, stream>>>(afP, WiP, enc_img_b, vf, vfP);
    p3_gemm<<<16, 256, 0, stream>>>(fmP, WmP, enc_mean_b, x1p0, h2p);
    enc_gemm<32><<<dim3(16, 40), 256, 0, stream>>>(vfP, WuaP, att_ba, imgp, nullptr);

    // hwa(0) only
    al_kernel<<<16, 256, 0, stream>>>(h2p, WaP, hw, WvP, embb, captions, -1,
                                      psumP, tlogs, 16);
    for (int s = 0; s < kNS; ++s) {
        unsigned short* x1c = (s & 1) ? x1p1 : x1p0;
        unsigned short* x1n = (s & 1) ? x1p0 : x1p1;
        unsigned short* x2c = (s & 1) ? x2p1 : x2p0;
        unsigned short* x2n = (s & 1) ? x2p0 : x2p1;
        attn_fused<<<64, 256, 0, stream>>>(hw, imgp, att_w, vf, video_mask,
                                           Wemb, captions, s, x1c);
        gates_cell<96><<<64, 512, 0, stream>>>(x1c, W1p, bsum1, c1,
                                               x1n, 2048, x2c, 0);
        gates_cell<64><<<64, 512, 0, stream>>>(x2c, W2p, bsum2, c2,
                                               x2n, 1024, h2p, 0);
        // logits(s) + hwa(s+1) fused; last step: logits only
        if (s < kNS - 1)
            al_kernel<<<266, 256, 0, stream>>>(h2p, WaP, hw, WvP, embb, captions, s,
                                               psumP, tlogs, 16);
        else
            al_kernel<<<250, 256, 0, stream>>>(h2p, WaP, hw, WvP, embb, captions, s,
                                               psumP, tlogs, 0);
    }
    final_loss<<<kNS, 256, 0, stream>>>(psumP, tlogs, msum, (float*)d_out);
}

// Round 6
// 2198.117 us; speedup vs baseline: 4.0773x; 1.0973x over previous
//
#include <hip/hip_runtime.h>
#include <stdint.h>

constexpr int kB   = 64;
constexpr int kTV  = 40;
constexpr int kF   = 2048;
constexpr int kH   = 1024;
constexpr int kV   = 32000;
constexpr int kNS  = 30;
constexpr int kCAP = 31;

typedef __attribute__((ext_vector_type(8))) short bf16x8;
typedef __attribute__((ext_vector_type(4))) float f32x4;

__device__ __forceinline__ float sigm(float x) { return 1.f / (1.f + __expf(-x)); }
__device__ __forceinline__ float tanh_fast(float x) {
    float e = __expf(2.f * x);
    return 1.f - 2.f / (e + 1.f);
}
__device__ __forceinline__ unsigned short f2bf(float x) {
    unsigned u = __float_as_uint(x);
    return (unsigned short)((u + 0x7fffu + ((u >> 16) & 1u)) >> 16);
}

__device__ __forceinline__ void gl16(const unsigned short* g, unsigned short* lds) {
    __builtin_amdgcn_global_load_lds(
        (const __attribute__((address_space(1))) unsigned int*)(g),
        (__attribute__((address_space(3))) unsigned int*)(lds), 16, 0, 0);
}

template <int N>
__device__ __forceinline__ void waitv() {
    asm volatile("s_waitcnt vmcnt(%0)" :: "n"(N) : "memory");
}
__device__ __forceinline__ void barrier_raw() {
    __builtin_amdgcn_s_barrier();
    asm volatile("" ::: "memory");
}

// A-packed layout: [kt][ms][lane][j]; (row,col): ms=row>>4,
// lane=(row&15)+16*((kc>>2)&3), j=(kc&3)+4*(kc>>4), kc=col&31, kt=col>>5.
__device__ __forceinline__ void store_packedA(unsigned short* base, int row, int col,
                                              unsigned short v) {
    int kt = col >> 5, kc = col & 31, ms = row >> 4;
    int l = (row & 15) + (((kc >> 2) & 3) << 4);
    int j = (kc & 3) + ((kc >> 4) << 2);
    base[((((size_t)kt * 4 + ms) * 64 + l) << 3) + j] = v;
}

// ---------------- 3-deep pipelined MFMA K-loop (one 4-wave group) ----------------
template <int NSPW, int KT>
__device__ __forceinline__ void mfma_kloop(
    const unsigned short* __restrict__ Ap, const unsigned short* __restrict__ Bp,
    unsigned short* Asm, unsigned short* Bsm, int w, int l, f32x4 acc[4][NSPW])
{
    constexpr int BSTEP = 2048 * NSPW;
    constexpr int LPT = 1 + NSPW;
    auto stage = [&](int t, int slot) {
        gl16(Ap + (size_t)t * 2048 + w * 512 + l * 8, Asm + slot * 2048 + w * 512);
#pragma unroll
        for (int i = 0; i < NSPW; ++i)
            gl16(Bp + (size_t)t * BSTEP + (w * NSPW + i) * 512 + l * 8,
                 Bsm + slot * BSTEP + (w * NSPW + i) * 512);
    };
    stage(0, 0); stage(1, 1); stage(2, 2);
#pragma unroll 1
    for (int t = 0; t < KT; ++t) {
        int slot = t % 3;
        int rem = KT - 1 - t;
        if (rem >= 2) waitv<2 * LPT>();
        else if (rem == 1) waitv<LPT>();
        else waitv<0>();
        barrier_raw();
        bf16x8 bfr[NSPW], afr[4];
#pragma unroll
        for (int i = 0; i < NSPW; ++i)
            bfr[i] = *(const bf16x8*)(Bsm + slot * BSTEP + ((w * NSPW + i) * 64 + l) * 8);
#pragma unroll
        for (int ms = 0; ms < 4; ++ms)
            afr[ms] = *(const bf16x8*)(Asm + slot * 2048 + (ms * 64 + l) * 8);
#pragma unroll
        for (int ms = 0; ms < 4; ++ms)
#pragma unroll
            for (int i = 0; i < NSPW; ++i)
                acc[ms][i] = __builtin_amdgcn_mfma_f32_16x16x32_bf16(
                    afr[ms], bfr[i], acc[ms][i], 0, 0, 0);
        __builtin_amdgcn_sched_barrier(0);
        barrier_raw();
        if (t + 3 < KT) stage(t + 3, slot);
    }
}

// ---------------- packing kernels (setup) ----------------
__global__ __launch_bounds__(256) void pack_rm(
    const float* __restrict__ p0, int ld0, int ksplit,
    const float* __restrict__ p1, int ld1,
    int NGRP, int GS, int HS, int KT,
    unsigned short* __restrict__ out)
{
    __shared__ unsigned short tile[16][136];
    int kb = blockIdx.x * 128;
    int grp = blockIdx.y;
    int row0 = (grp % NGRP) * GS + (grp / NGRP) * HS;
    int tid = threadIdx.x;
    int r = tid >> 5, c4 = (tid & 31) * 4;
#pragma unroll
    for (int pass = 0; pass < 2; ++pass) {
        int rr = r + pass * 8;
        int row = row0 + rr;
        int k = kb + c4;
        float4 v;
        if (k < ksplit) v = *(const float4*)(p0 + (size_t)row * ld0 + k);
        else            v = *(const float4*)(p1 + (size_t)row * ld1 + (k - ksplit));
        ushort4 o; o.x = f2bf(v.x); o.y = f2bf(v.y); o.z = f2bf(v.z); o.w = f2bf(v.w);
        *(ushort4*)&tile[rr][c4] = o;
    }
    __syncthreads();
    int ktl = tid >> 6, l = tid & 63, ul = l & 15, q = (l >> 4) & 3;
    __align__(16) unsigned short o2[8];
#pragma unroll
    for (int j = 0; j < 8; ++j) {
        int kc = (j & 3) + q * 4 + ((j >> 2) << 4);
        o2[j] = tile[ul][ktl * 32 + kc];
    }
    int kt = (kb >> 5) + ktl;
    size_t base = (((size_t)(grp / NGRP) * KT + kt) * NGRP + (grp % NGRP)) * 512;
    *(uint4*)(out + base + (size_t)l * 8) = *(const uint4*)o2;
}

__global__ __launch_bounds__(256) void pack_cm(const float* __restrict__ W,
                                               unsigned short* __restrict__ out)
{
    __shared__ unsigned short tile[32][136];
    int n0 = blockIdx.x * 128, k0 = blockIdx.y * 32;
    int tid = threadIdx.x;
    int r = tid >> 5, c4 = (tid & 31) * 4;
#pragma unroll
    for (int pass = 0; pass < 4; ++pass) {
        int rr = r + pass * 8;
        float4 v = *(const float4*)(W + (size_t)(k0 + rr) * kV + n0 + c4);
        ushort4 o; o.x = f2bf(v.x); o.y = f2bf(v.y); o.z = f2bf(v.z); o.w = f2bf(v.w);
        *(ushort4*)&tile[rr][c4] = o;
    }
    __syncthreads();
    int ns = tid >> 5, lp = (tid & 31) * 2;
    size_t base = (((size_t)blockIdx.x * 32 + blockIdx.y) * 8 + ns) * 512;
    __align__(16) unsigned short o2[16];
#pragma unroll
    for (int li = 0; li < 2; ++li) {
        int l = lp + li, ul = l & 15, q = (l >> 4) & 3;
#pragma unroll
        for (int j = 0; j < 8; ++j) {
            int kc = (j & 3) + q * 4 + ((j >> 2) << 4);
            o2[li * 8 + j] = tile[kc][ns * 16 + ul];
        }
    }
    *(uint4*)(out + base + lp * 8) = *(const uint4*)&o2[0];
    *(uint4*)(out + base + lp * 8 + 8) = *(const uint4*)&o2[8];
}

// 4 small [K][1024] weights -> B-tiles (S=4), merged into one dispatch
__global__ __launch_bounds__(256) void pack_kn4(
    const float* __restrict__ Wi, const float* __restrict__ Wm,
    const float* __restrict__ Wua, const float* __restrict__ Wa,
    unsigned short* __restrict__ oi, unsigned short* __restrict__ om,
    unsigned short* __restrict__ oua, unsigned short* __restrict__ oa)
{
    int bid = blockIdx.x;
    const float* W; unsigned short* out; int K, rel;
    if (bid < 1024)       { W = Wi;  out = oi;  K = 2048; rel = bid; }
    else if (bid < 2048)  { W = Wm;  out = om;  K = 2048; rel = bid - 1024; }
    else if (bid < 2560)  { W = Wua; out = oua; K = 1024; rel = bid - 2048; }
    else                  { W = Wa;  out = oa;  K = 1024; rel = bid - 2560; }
    size_t tid = (size_t)rel * 256 + threadIdx.x;
    int l = tid & 63;
    size_t f = tid >> 6;
    int ns = f & 3; f >>= 2;
    int KT = K >> 5;
    int kt = f % KT; int nb = f / KT;
    int n = nb * 64 + ns * 16 + (l & 15);
    int kb = kt * 32 + ((l >> 4) & 3) * 4;
    __align__(16) unsigned short o[8];
#pragma unroll
    for (int j = 0; j < 8; ++j) {
        int k = kb + (j & 3) + ((j >> 2) << 4);
        o[j] = f2bf(W[(size_t)k * 1024 + n]);
    }
    *(uint4*)(out + tid * 8) = *(const uint4*)o;
}

// mean_f (blocks 0..63) + bias/mask prep (blocks 64..96) merged
__global__ __launch_bounds__(256) void prep_mean(
    const float* __restrict__ af, float* __restrict__ fm,
    const float* __restrict__ bih1, const float* __restrict__ bhh1,
    const float* __restrict__ bih2, const float* __restrict__ bhh2,
    const float* __restrict__ capmask,
    float* __restrict__ bsum1, float* __restrict__ bsum2, float* __restrict__ msum)
{
    int tid = threadIdx.x;
    if (blockIdx.x < 64) {
        int b = blockIdx.x;
        const float* base = af + (size_t)b * kTV * kF;
        float a[8] = {};
        for (int t = 0; t < kTV; ++t) {
            const float* rp = base + (size_t)t * kF + tid * 8;
            float4 v0 = *(const float4*)rp;
            float4 v1 = *(const float4*)(rp + 4);
            a[0] += v0.x; a[1] += v0.y; a[2] += v0.z; a[3] += v0.w;
            a[4] += v1.x; a[5] += v1.y; a[6] += v1.z; a[7] += v1.w;
        }
        float* op = fm + (size_t)b * kF + tid * 8;
#pragma unroll
        for (int j = 0; j < 8; ++j) op[j] = a[j] * (1.f / kTV);
    } else {
        int g = (blockIdx.x - 64) * 256 + tid;
        if (g < 4096) bsum1[g] = bih1[g] + bhh1[g];
        else if (g < 8192) { int j = g - 4096; bsum2[j] = bih2[j] + bhh2[j]; }
        else if (g < 8192 + kNS) {
            int t = g - 8192;
            float s = 0.f;
            for (int b = 0; b < kB; ++b) s += capmask[b * kCAP + t + 1];
            msum[t] = s;
        }
    }
}

// ---------------- encoder GEMM: outF = A@B + bias (+optional packed copy) ----------------
template <int KT>
__global__ __launch_bounds__(256) void enc_gemm(
    const unsigned short* __restrict__ Ap, const unsigned short* __restrict__ Bp,
    const float* __restrict__ bias, float* __restrict__ outF,
    unsigned short* __restrict__ outP)
{
    __shared__ unsigned short Asm[3][2048];
    __shared__ unsigned short Bsm[3][2048];
    int tid = threadIdx.x, w = tid >> 6, l = tid & 63;
    int nb = blockIdx.x, mb = blockIdx.y;
    f32x4 acc[4][1] = {};
    mfma_kloop<1, KT>(Ap + (size_t)mb * KT * 2048, Bp + (size_t)nb * KT * 2048,
                      &Asm[0][0], &Bsm[0][0], w, l, acc);
    int ul = l & 15, sg = l >> 4;
    int n = nb * 64 + w * 16 + ul;
    float bv = bias[n];
#pragma unroll
    for (int ms = 0; ms < 4; ++ms)
#pragma unroll
        for (int r = 0; r < 4; ++r) {
            int rl = ms * 16 + sg * 4 + r;
            int row = mb * 64 + rl;
            float v = acc[ms][0][r] + bv;
            outF[(size_t)row * kH + n] = v;
            if (outP) store_packedA(outP + (size_t)mb * 65536, rl, n, f2bf(v));
        }
}

__global__ __launch_bounds__(256) void p3_gemm(
    const unsigned short* __restrict__ Ap, const unsigned short* __restrict__ Bp,
    const float* __restrict__ bias, unsigned short* __restrict__ xcat1p,
    unsigned short* __restrict__ h2hist0)
{
    __shared__ unsigned short Asm[3][2048];
    __shared__ unsigned short Bsm[3][2048];
    int tid = threadIdx.x, w = tid >> 6, l = tid & 63;
    int nb = blockIdx.x;
    f32x4 acc[4][1] = {};
    mfma_kloop<1, 64>(Ap, Bp + (size_t)nb * 64 * 2048, &Asm[0][0], &Bsm[0][0], w, l, acc);
    int ul = l & 15, sg = l >> 4;
    int n = nb * 64 + w * 16 + ul;
    float bv = bias[n];
#pragma unroll
    for (int ms = 0; ms < 4; ++ms)
#pragma unroll
        for (int r = 0; r < 4; ++r) {
            int row = ms * 16 + sg * 4 + r;
            unsigned short hb = f2bf(acc[ms][0][r] + bv);
            store_packedA(xcat1p, row, 2048 + n, hb);
            store_packedA(h2hist0, row, n, hb);
        }
}

// ---------------- hwa: hw = h_prev @ att_Wa (512 thr, 2-way K-split) ----------------
__global__ __launch_bounds__(512) void hwa_gemm(
    const unsigned short* __restrict__ h2p, const unsigned short* __restrict__ WaP,
    float* __restrict__ hw)
{
    __shared__ __align__(16) char smem[49152];
    float* rsum = (float*)smem;                     // [4][64][17] aliased post-kloop
    int tid = threadIdx.x, w = tid >> 6, l = tid & 63, nb = blockIdx.x;
    int h = w >> 2, w4 = w & 3;
    unsigned short* Asm = (unsigned short*)(smem + h * 24576);
    unsigned short* Bsm = Asm + 6144;
    f32x4 acc[4][1] = {};
    mfma_kloop<1, 16>(h2p + (size_t)h * 16 * 2048,
                      WaP + (size_t)nb * 32 * 2048 + (size_t)h * 16 * 2048,
                      Asm, Bsm, w4, l, acc);
    int ul = l & 15, sg = l >> 4;
    __syncthreads();
    if (h == 1) {
#pragma unroll
        for (int ms = 0; ms < 4; ++ms)
#pragma unroll
            for (int r = 0; r < 4; ++r)
                rsum[((w4 * 64) + ms * 16 + sg * 4 + r) * 17 + ul] = acc[ms][0][r];
    }
    __syncthreads();
    if (h == 0) {
        int n = nb * 64 + w4 * 16 + ul;
#pragma unroll
        for (int ms = 0; ms < 4; ++ms)
#pragma unroll
            for (int r = 0; r < 4; ++r) {
                int row = ms * 16 + sg * 4 + r;
                hw[(size_t)row * kH + n] =
                    acc[ms][0][r] + rsum[((w4 * 64) + row) * 17 + ul];
            }
    }
}

// ---------------- fused attention (per batch row) ----------------
__global__ __launch_bounds__(256) void attn_fused(
    const float* __restrict__ hw, const float* __restrict__ imgp,
    const float* __restrict__ attw, const float* __restrict__ vf,
    const float* __restrict__ vmask, const float* __restrict__ Wemb,
    const int* __restrict__ captions, int s, unsigned short* __restrict__ xcat1p)
{
    __shared__ float hwv[kH];
    __shared__ float es[48];
    int b = blockIdx.x, tid = threadIdx.x;
    for (int i = tid; i < kH; i += 256) hwv[i] = hw[(size_t)b * kH + i];
    __syncthreads();
    int w = tid >> 6, l = tid & 63;
    for (int t = w; t < kTV; t += 4) {
        const float* ip = imgp + ((size_t)b * kTV + t) * kH;
        float p = 0.f;
#pragma unroll
        for (int hh = 0; hh < 16; ++hh) {
            int h = hh * 64 + l;
            p += tanh_fast(hwv[h] + ip[h]) * attw[h];
        }
        for (int off = 32; off; off >>= 1) p += __shfl_down(p, off);
        if (l == 0) es[t] = p;
    }
    __syncthreads();
    float mx = -1e30f;
    for (int t = 0; t < kTV; ++t) mx = fmaxf(mx, es[t]);
    const float* vm = vmask + b * kTV;
    float den = 0.f;
    for (int t = 0; t < kTV; ++t) den += vm[t] * __expf(es[t] - mx);
    den = den + (den == 0.f ? 1.f : 0.f) + 1e-9f;
    int h0 = tid * 4;
    float4 av = {0.f, 0.f, 0.f, 0.f};
    for (int t = 0; t < kTV; ++t) {
        float wgt = vm[t] * __expf(es[t] - mx) / den;
        float4 v = *(const float4*)(vf + ((size_t)b * kTV + t) * kH + h0);
        av.x += wgt * v.x; av.y += wgt * v.y; av.z += wgt * v.z; av.w += wgt * v.w;
    }
    store_packedA(xcat1p, b, 1024 + h0 + 0, f2bf(av.x));
    store_packedA(xcat1p, b, 1024 + h0 + 1, f2bf(av.y));
    store_packedA(xcat1p, b, 1024 + h0 + 2, f2bf(av.z));
    store_packedA(xcat1p, b, 1024 + h0 + 3, f2bf(av.w));
    int word = captions[b * kCAP + s];
    float4 e4 = *(const float4*)(Wemb + (size_t)word * kH + h0);
    store_packedA(xcat1p, b, h0 + 0, f2bf(e4.x));
    store_packedA(xcat1p, b, h0 + 1, f2bf(e4.y));
    store_packedA(xcat1p, b, h0 + 2, f2bf(e4.z));
    store_packedA(xcat1p, b, h0 + 3, f2bf(e4.w));
}

// ---------------- gates GEMM + fused LSTM cell (1024 thr, 4-way K-split) ----------------
template <int KT>
__global__ __launch_bounds__(1024) void gates_cell(
    const unsigned short* __restrict__ Ap, const unsigned short* __restrict__ Bp,
    const float* __restrict__ bsum, float* __restrict__ cbuf,
    unsigned short* __restrict__ dA, int ofsA,
    unsigned short* __restrict__ dB, int ofsB)
{
    __shared__ __align__(16) char smem[98304];     // 4 groups x 24 KB staging
    float* gsm = (float*)smem;                     // [8][64][17] fp32, aliased
    constexpr int KQ = KT / 4;
    int tid = threadIdx.x, w = tid >> 6, l = tid & 63, nb = blockIdx.x;
    int g = w >> 2, w4 = w & 3;
    unsigned short* Asm = (unsigned short*)(smem + g * 24576);
    unsigned short* Bsm = Asm + 6144;
    f32x4 acc[4][1] = {};
    mfma_kloop<1, KQ>(Ap + (size_t)g * KQ * 2048,
                      Bp + (size_t)nb * KT * 2048 + (size_t)g * KQ * 2048,
                      Asm, Bsm, w4, l, acc);
    int ul = l & 15, sg = l >> 4;
    float bv = (g == 0) ? bsum[w4 * 1024 + nb * 16 + ul] : 0.f;
    __syncthreads();                               // all kloop LDS traffic done
    int sl = (g & 1) * 4 + w4;
    if (g < 2) {
#pragma unroll
        for (int ms = 0; ms < 4; ++ms)
#pragma unroll
            for (int r = 0; r < 4; ++r)
                gsm[(sl * 64 + ms * 16 + sg * 4 + r) * 17 + ul] = acc[ms][0][r] + bv;
    }
    __syncthreads();
    if (g >= 2) {
#pragma unroll
        for (int ms = 0; ms < 4; ++ms)
#pragma unroll
            for (int r = 0; r < 4; ++r)
                gsm[(sl * 64 + ms * 16 + sg * 4 + r) * 17 + ul] += acc[ms][0][r];
    }
    __syncthreads();
    {
        int row = tid >> 4, uc = tid & 15, u = nb * 16 + uc;
        float gi = gsm[((0 * 64) + row) * 17 + uc] + gsm[((4 * 64) + row) * 17 + uc];
        float gf = gsm[((1 * 64) + row) * 17 + uc] + gsm[((5 * 64) + row) * 17 + uc];
        float gg = gsm[((2 * 64) + row) * 17 + uc] + gsm[((6 * 64) + row) * 17 + uc];
        float go = gsm[((3 * 64) + row) * 17 + uc] + gsm[((7 * 64) + row) * 17 + uc];
        float c = sigm(gf) * cbuf[(size_t)row * kH + u] + sigm(gi) * tanh_fast(gg);
        cbuf[(size_t)row * kH + u] = c;
        unsigned short hb = f2bf(sigm(go) * tanh_fast(c));
        store_packedA(dA, row, ofsA + u, hb);
        store_packedA(dB, row, ofsB + u, hb);
    }
}

// ---------------- deferred logits: all steps, one dispatch ----------------
__global__ __launch_bounds__(256) void logits_all(
    const unsigned short* __restrict__ h2hist, const unsigned short* __restrict__ WvP,
    const float* __restrict__ embb, const int* __restrict__ captions,
    float* __restrict__ psumP, float* __restrict__ tlogs)
{
    __shared__ unsigned short Asm[3][2048];
    __shared__ unsigned short Bsm2[3][4096];
    __shared__ float rsum[4][64];
    __shared__ int stgt[64];
    int nb = blockIdx.x, s = blockIdx.y;
    int tid = threadIdx.x, w = tid >> 6, l = tid & 63, ul = l & 15, sg = l >> 4;
    if (tid < 64) stgt[tid] = captions[tid * kCAP + s + 1];
    f32x4 acc[4][2] = {};
    mfma_kloop<2, 32>(h2hist + (size_t)(s + 1) * 65536, WvP + (size_t)nb * 32 * 4096,
                      &Asm[0][0], &Bsm2[0][0], w, l, acc);
    int n0 = nb * 128 + (2 * w + 0) * 16 + ul;
    int n1 = nb * 128 + (2 * w + 1) * 16 + ul;
    float b0 = embb[n0], b1 = embb[n1];
    float ls[4][4];
#pragma unroll
    for (int ms = 0; ms < 4; ++ms)
#pragma unroll
        for (int r = 0; r < 4; ++r) {
            int row = ms * 16 + sg * 4 + r;
            float v0 = acc[ms][0][r] + b0, v1 = acc[ms][1][r] + b1;
            ls[ms][r] = __expf(v0) + __expf(v1);
            if (n0 == stgt[row]) tlogs[s * 64 + row] = v0;
            if (n1 == stgt[row]) tlogs[s * 64 + row] = v1;
        }
#pragma unroll
    for (int m = 1; m < 16; m <<= 1)
#pragma unroll
        for (int ms = 0; ms < 4; ++ms)
#pragma unroll
            for (int r = 0; r < 4; ++r)
                ls[ms][r] += __shfl_xor(ls[ms][r], m);
    if (ul == 0)
#pragma unroll
        for (int ms = 0; ms < 4; ++ms)
#pragma unroll
            for (int r = 0; r < 4; ++r)
                rsum[w][ms * 16 + sg * 4 + r] = ls[ms][r];
    __syncthreads();
    if (tid < 64)
        psumP[((size_t)s * 250 + nb) * 64 + tid] =
            rsum[0][tid] + rsum[1][tid] + rsum[2][tid] + rsum[3][tid];
}

// ---------------- final loss over all steps ----------------
__global__ __launch_bounds__(256) void final_loss(
    const float* __restrict__ psumP, const float* __restrict__ tlogs,
    const float* __restrict__ msum, float* __restrict__ out)
{
    __shared__ float sl[16000];
    int s = blockIdx.x, tid = threadIdx.x;
    const float* src = psumP + (size_t)s * 16000;
    for (int i = tid; i < 16000; i += 256) sl[i] = src[i];
    __syncthreads();
    if (tid < 64) {
        float tot = 0.f;
        for (int i = 0; i < 250; ++i) tot += sl[i * 64 + tid];
        float logp = tlogs[s * 64 + tid] - __logf(tot);
        float term = -logp * msum[s] * (1.f / 4096.f);
        for (int off = 32; off; off >>= 1) term += __shfl_down(term, off);
        if (tid == 0) atomicAdd(out, term);
    }
}

// ---------------- host ----------------
extern "C" void kernel_launch(void* const* d_in, const int* in_sizes, int n_in,
                              void* d_out, int out_size, void* d_ws, size_t ws_size,
                              hipStream_t stream)
{
    const float* action_feat = (const float*)d_in[1];
    const float* video_mask  = (const float*)d_in[3];
    const int*   captions    = (const int*)d_in[4];
    const float* capmask     = (const float*)d_in[5];
    const float* enc_img_W   = (const float*)d_in[6];
    const float* enc_img_b   = (const float*)d_in[7];
    const float* enc_mean_W  = (const float*)d_in[8];
    const float* enc_mean_b  = (const float*)d_in[9];
    const float* att_w       = (const float*)d_in[10];
    const float* att_Wa      = (const float*)d_in[11];
    const float* att_Ua      = (const float*)d_in[12];
    const float* att_ba      = (const float*)d_in[13];
    const float* Wemb        = (const float*)d_in[14];
    const float* embW        = (const float*)d_in[15];
    const float* embb        = (const float*)d_in[16];
    const float* W1ih        = (const float*)d_in[17];
    const float* W1hh        = (const float*)d_in[18];
    const float* b1ih        = (const float*)d_in[19];
    const float* b1hh        = (const float*)d_in[20];
    const float* W2ih        = (const float*)d_in[21];
    const float* W2hh        = (const float*)d_in[22];
    const float* b2ih        = (const float*)d_in[23];
    const float* b2hh        = (const float*)d_in[24];

    char* base = (char*)d_ws;
    size_t off = 0;
    auto alloc = [&](size_t bytes) {
        char* p = base + off;
        off = (off + bytes + 255) & ~(size_t)255;
        return p;
    };
    constexpr int BIG = 0x40000000;

    float* vf    = (float*)alloc((size_t)2560 * 1024 * 4);
    float* imgp  = (float*)alloc((size_t)2560 * 1024 * 4);
    float* fm    = (float*)alloc((size_t)64 * 2048 * 4);
    float* hw    = (float*)alloc((size_t)64 * 1024 * 4);
    float* bsum1 = (float*)alloc(4096 * 4);
    float* bsum2 = (float*)alloc(4096 * 4);
    float* msum  = (float*)alloc(32 * 4);
    float* psumP = (float*)alloc((size_t)kNS * 250 * 64 * 4);
    float* tlogs = (float*)alloc((size_t)kNS * 64 * 4);
    // zero-init block: x2p[2], c1, c2 contiguous
    unsigned short* x2p0 = (unsigned short*)alloc((size_t)64 * 2048 * 2);
    unsigned short* x2p1 = (unsigned short*)alloc((size_t)64 * 2048 * 2);
    float* c1    = (float*)alloc((size_t)64 * 1024 * 4);
    float* c2    = (float*)alloc((size_t)64 * 1024 * 4);
    size_t zlen  = (size_t)((char*)(c2 + 64 * 1024) - (char*)x2p0);

    unsigned short* x1p0 = (unsigned short*)alloc((size_t)64 * 3072 * 2);
    unsigned short* x1p1 = (unsigned short*)alloc((size_t)64 * 3072 * 2);
    unsigned short* h2hist = (unsigned short*)alloc((size_t)(kNS + 1) * 64 * 1024 * 2);
    unsigned short* afP  = (unsigned short*)alloc((size_t)2560 * 2048 * 2);
    unsigned short* vfP  = (unsigned short*)alloc((size_t)2560 * 1024 * 2);
    unsigned short* fmP  = (unsigned short*)alloc((size_t)64 * 2048 * 2);
    unsigned short* WiP  = (unsigned short*)alloc((size_t)2048 * 1024 * 2);
    unsigned short* WmP  = (unsigned short*)alloc((size_t)2048 * 1024 * 2);
    unsigned short* WuaP = (unsigned short*)alloc((size_t)1024 * 1024 * 2);
    unsigned short* WaP  = (unsigned short*)alloc((size_t)1024 * 1024 * 2);
    unsigned short* W1p  = (unsigned short*)alloc((size_t)3072 * 4096 * 2);
    unsigned short* W2p  = (unsigned short*)alloc((size_t)2048 * 4096 * 2);
    unsigned short* WvP  = (unsigned short*)alloc((size_t)1024 * 32000 * 2);
    if (off > ws_size) return;

    hipMemsetAsync(d_out, 0, 4, stream);
    hipMemsetAsync(x2p0, 0, zlen, stream);

    prep_mean<<<97, 256, 0, stream>>>(action_feat, fm, b1ih, b1hh, b2ih, b2hh,
                                      capmask, bsum1, bsum2, msum);
    pack_rm<<<dim3(16, 4), 256, 0, stream>>>(fm, 2048, BIG, nullptr, 0,
                                             4, 16, 64, 64, fmP);
    pack_rm<<<dim3(16, 160), 256, 0, stream>>>(action_feat, 2048, BIG, nullptr, 0,
                                               4, 16, 64, 64, afP);
    pack_rm<<<dim3(24, 256), 256, 0, stream>>>(W1ih, 2048, 2048, W1hh, 1024,
                                               4, 1024, 16, 96, W1p);
    pack_rm<<<dim3(16, 256), 256, 0, stream>>>(W2ih, 1024, 1024, W2hh, 1024,
                                               4, 1024, 16, 64, W2p);
    pack_kn4<<<3072, 256, 0, stream>>>(enc_img_W, enc_mean_W, att_Ua, att_Wa,
                                       WiP, WmP, WuaP, WaP);
    pack_cm<<<dim3(250, 32), 256, 0, stream>>>(embW, WvP);

    enc_gemm<64><<<dim3(16, 40), 256, 0, stream>>>(afP, WiP, enc_img_b, vf, vfP);
    p3_gemm<<<16, 256, 0, stream>>>(fmP, WmP, enc_mean_b, x1p0, h2hist);
    enc_gemm<32><<<dim3(16, 40), 256, 0, stream>>>(vfP, WuaP, att_ba, imgp, nullptr);

    for (int s = 0; s < kNS; ++s) {
        unsigned short* x1c = (s & 1) ? x1p1 : x1p0;
        unsigned short* x1n = (s & 1) ? x1p0 : x1p1;
        unsigned short* x2c = (s & 1) ? x2p1 : x2p0;
        unsigned short* x2n = (s & 1) ? x2p0 : x2p1;
        hwa_gemm<<<16, 512, 0, stream>>>(h2hist + (size_t)s * 65536, WaP, hw);
        attn_fused<<<64, 256, 0, stream>>>(hw, imgp, att_w, vf, video_mask,
                                           Wemb, captions, s, x1c);
        gates_cell<96><<<64, 1024, 0, stream>>>(x1c, W1p, bsum1, c1,
                                                x1n, 2048, x2c, 0);
        gates_cell<64><<<64, 1024, 0, stream>>>(x2c, W2p, bsum2, c2,
                                                x2n, 1024,
                                                h2hist + (size_t)(s + 1) * 65536, 0);
    }
    logits_all<<<dim3(250, kNS), 256, 0, stream>>>(h2hist, WvP, embb, captions,
                                                   psumP, tlogs);
    final_loss<<<kNS, 256, 0, stream>>>(psumP, tlogs, msum, (float*)d_out);
}